// Round 1
// baseline (1956.095 us; speedup 1.0000x reference)
//
#include <hip/hip_runtime.h>

static constexpr int N = 32768;
static constexpr int K = 4096;
static constexpr int D = 512;

// ---------------------------------------------------------------------------
// Kernel 1: replicate np.sum(a*a, axis=-1) for rows of 512 floats, using
// numpy's pairwise_sum order exactly:
//   n=512 -> (pw256 + pw256); 256 -> (pw128 + pw128);
//   pw128: 8 accumulators r[j] = sum_{i} a[j+8i] (sequential, 16 terms),
//          combined ((r0+r1)+(r2+r3)) + ((r4+r5)+(r6+r7)).
// 32 lanes per row: lane = blk*8 + j; blk in [0,4) over 128-elem blocks.
// Combine via shfl_xor tree (masks 1,2,4 within block; 8,16 across blocks)
// which reproduces the exact fp32 add tree (fp add is commutative bitwise).
// No FMA contraction: squares rounded separately like numpy's x*x array.
// ---------------------------------------------------------------------------
__global__ void rowsq_kernel(const float* __restrict__ a, float* __restrict__ out,
                             int rows) {
  int tid = threadIdx.x;
  int row = blockIdx.x * 8 + (tid >> 5);
  if (row >= rows) return;
  int l = tid & 31;
  const float* p = a + (size_t)row * D + (l >> 3) * 128 + (l & 7);
  float r = 0.f;
#pragma unroll
  for (int i = 0; i < 16; ++i) {
    float v = p[i * 8];
    r = __fadd_rn(r, __fmul_rn(v, v));  // fl(r + fl(v^2)), no contraction
  }
  r = __fadd_rn(r, __shfl_xor(r, 1));
  r = __fadd_rn(r, __shfl_xor(r, 2));
  r = __fadd_rn(r, __shfl_xor(r, 4));
  r = __fadd_rn(r, __shfl_xor(r, 8));
  r = __fadd_rn(r, __shfl_xor(r, 16));
  if (l == 0) out[row] = r;
}

// ---------------------------------------------------------------------------
// Kernel 2: fused distance GEMM + running argmin.
// Block = 256 threads (16x16), tile BM=64 rows x BK=128 codewords, BD=32.
// Each thread: 4x8 micro-tile of dot-product accumulators (fp32 FMA).
// Score computed in the ref's exact elementwise order:
//   t = fl(x_sq - fl(2*dot)); d = fl(t + c_sq)   (magnitude ~513 like ref)
// Running (min,idx) per thread-row; k ascending => strict '<' keeps first.
// Final cross-thread reduce with (val, then lower idx) tie-break = np.argmin.
// ---------------------------------------------------------------------------
static constexpr int BM = 64;
static constexpr int BK = 128;
static constexpr int BD = 32;

__global__ __launch_bounds__(256) void argmin_kernel(
    const float* __restrict__ x, const float* __restrict__ cb,
    const float* __restrict__ xsq, const float* __restrict__ csq,
    float* __restrict__ zout) {
  __shared__ float xs[BD][BM];   // 8 KiB, transposed x tile
  __shared__ float cs[BD][BK];   // 16 KiB, transposed codebook tile
  __shared__ float mv[BM][16];   // 4 KiB
  __shared__ int   mi[BM][16];   // 4 KiB

  int tid = threadIdx.x;
  int tx = tid & 15;   // col group: covers k_local = tx*8 .. tx*8+7
  int ty = tid >> 4;   // row group: covers m_local = ty*4 .. ty*4+3
  int row0 = blockIdx.x * BM;

  float bestv[4];
  int besti[4];
  float xsqr[4];
#pragma unroll
  for (int i = 0; i < 4; ++i) {
    bestv[i] = 3.4e38f;
    besti[i] = 0x7fffffff;
    xsqr[i] = xsq[row0 + ty * 4 + i];
  }

  for (int kt = 0; kt < K; kt += BK) {
    float acc[4][8];
#pragma unroll
    for (int i = 0; i < 4; ++i)
#pragma unroll
      for (int j = 0; j < 8; ++j) acc[i][j] = 0.f;

    for (int dt = 0; dt < D; dt += BD) {
      __syncthreads();
      {  // stage x tile: r = tid/4 (64 rows), d0 = (tid%4)*8
        int r = tid >> 2, d0 = (tid & 3) * 8;
        const float* src = x + (size_t)(row0 + r) * D + dt + d0;
        float4 v0 = *(const float4*)(src);
        float4 v1 = *(const float4*)(src + 4);
        xs[d0 + 0][r] = v0.x; xs[d0 + 1][r] = v0.y;
        xs[d0 + 2][r] = v0.z; xs[d0 + 3][r] = v0.w;
        xs[d0 + 4][r] = v1.x; xs[d0 + 5][r] = v1.y;
        xs[d0 + 6][r] = v1.z; xs[d0 + 7][r] = v1.w;
      }
      {  // stage codebook tile: kk = tid/2 (128 cols), d0 = (tid%2)*16
        int kk = tid >> 1, d0 = (tid & 1) * 16;
        const float* src = cb + (size_t)(kt + kk) * D + dt + d0;
        float4 v0 = *(const float4*)(src);
        float4 v1 = *(const float4*)(src + 4);
        float4 v2 = *(const float4*)(src + 8);
        float4 v3 = *(const float4*)(src + 12);
        cs[d0 + 0][kk] = v0.x;  cs[d0 + 1][kk] = v0.y;
        cs[d0 + 2][kk] = v0.z;  cs[d0 + 3][kk] = v0.w;
        cs[d0 + 4][kk] = v1.x;  cs[d0 + 5][kk] = v1.y;
        cs[d0 + 6][kk] = v1.z;  cs[d0 + 7][kk] = v1.w;
        cs[d0 + 8][kk] = v2.x;  cs[d0 + 9][kk] = v2.y;
        cs[d0 + 10][kk] = v2.z; cs[d0 + 11][kk] = v2.w;
        cs[d0 + 12][kk] = v3.x; cs[d0 + 13][kk] = v3.y;
        cs[d0 + 14][kk] = v3.z; cs[d0 + 15][kk] = v3.w;
      }
      __syncthreads();
#pragma unroll 4
      for (int d = 0; d < BD; ++d) {
        float xa[4], cv[8];
        *(float4*)&xa[0] = *(const float4*)&xs[d][ty * 4];
        *(float4*)&cv[0] = *(const float4*)&cs[d][tx * 8];
        *(float4*)&cv[4] = *(const float4*)&cs[d][tx * 8 + 4];
#pragma unroll
        for (int i = 0; i < 4; ++i)
#pragma unroll
          for (int j = 0; j < 8; ++j)
            acc[i][j] = fmaf(xa[i], cv[j], acc[i][j]);
      }
    }

    // score + running argmin (ref order: (x_sq - 2*dot) + c_sq)
#pragma unroll
    for (int j = 0; j < 8; ++j) {
      int k = kt + tx * 8 + j;
      float cq = csq[k];
#pragma unroll
      for (int i = 0; i < 4; ++i) {
        float two = __fadd_rn(acc[i][j], acc[i][j]);  // exact 2*dot
        float t = __fsub_rn(xsqr[i], two);
        float dsc = __fadd_rn(t, cq);
        if (dsc < bestv[i]) { bestv[i] = dsc; besti[i] = k; }
      }
    }
  }

  __syncthreads();
#pragma unroll
  for (int i = 0; i < 4; ++i) {
    mv[ty * 4 + i][tx] = bestv[i];
    mi[ty * 4 + i][tx] = besti[i];
  }
  __syncthreads();
  if (tid < BM) {
    float bv = mv[tid][0];
    int bi = mi[tid][0];
#pragma unroll
    for (int t = 1; t < 16; ++t) {
      float v = mv[tid][t];
      int ii = mi[tid][t];
      if (v < bv || (v == bv && ii < bi)) { bv = v; bi = ii; }
    }
    zout[row0 + tid] = (float)bi;  // exact for idx < 2^24
  }
}

// ---------------------------------------------------------------------------
// Kernel 3: gather q = cb[Z], q_with_st = x + (q - x), per-block partial
// sums of (q - x)^2 into workspace. float4 vectorized. 2048 blocks x 256
// threads x 8 float4 iters = exactly N*D/4.
// ---------------------------------------------------------------------------
__global__ __launch_bounds__(256) void gather_kernel(
    const float* __restrict__ x, const float* __restrict__ cb,
    const float* __restrict__ zf, float* __restrict__ qout,
    float* __restrict__ partial) {
  __shared__ float red[256];
  const size_t TOT4 = (size_t)N * D / 4;
  size_t t0 = (size_t)blockIdx.x * 256 + threadIdx.x;
  float lsum = 0.f;
  for (size_t f = t0; f < TOT4; f += (size_t)2048 * 256) {
    int n = (int)(f >> 7);      // f / (D/4)
    int d4 = (int)(f & 127);
    int z = (int)zf[n];
    float4 xv = ((const float4*)x)[f];
    float4 qv = *(const float4*)(cb + (size_t)z * D + d4 * 4);
    float dx0 = __fsub_rn(qv.x, xv.x);
    float dx1 = __fsub_rn(qv.y, xv.y);
    float dx2 = __fsub_rn(qv.z, xv.z);
    float dx3 = __fsub_rn(qv.w, xv.w);
    float4 o;
    o.x = __fadd_rn(xv.x, dx0);
    o.y = __fadd_rn(xv.y, dx1);
    o.z = __fadd_rn(xv.z, dx2);
    o.w = __fadd_rn(xv.w, dx3);
    ((float4*)qout)[f] = o;
    lsum += dx0 * dx0 + dx1 * dx1 + dx2 * dx2 + dx3 * dx3;
  }
  red[threadIdx.x] = lsum;
  __syncthreads();
  for (int s = 128; s > 0; s >>= 1) {
    if (threadIdx.x < s) red[threadIdx.x] += red[threadIdx.x + s];
    __syncthreads();
  }
  if (threadIdx.x == 0) partial[blockIdx.x] = red[0];
}

// ---------------------------------------------------------------------------
// Kernel 4: deterministic reduce of 2048 partials -> both loss slots.
// ---------------------------------------------------------------------------
__global__ __launch_bounds__(256) void loss_kernel(const float* __restrict__ partial,
                                                   float* __restrict__ loss_out) {
  __shared__ float red[256];
  float s = 0.f;
  for (int i = threadIdx.x; i < 2048; i += 256) s += partial[i];
  red[threadIdx.x] = s;
  __syncthreads();
  for (int k = 128; k > 0; k >>= 1) {
    if (threadIdx.x < k) red[threadIdx.x] += red[threadIdx.x + k];
    __syncthreads();
  }
  if (threadIdx.x == 0) {
    float m = red[0] / (float)((size_t)N * D);
    loss_out[0] = m;  // vq_loss
    loss_out[1] = m;  // commitment_loss (identical forward value)
  }
}

extern "C" void kernel_launch(void* const* d_in, const int* in_sizes, int n_in,
                              void* d_out, int out_size, void* d_ws, size_t ws_size,
                              hipStream_t stream) {
  const float* x = (const float*)d_in[0];
  const float* cb = (const float*)d_in[1];
  float* out = (float*)d_out;

  // d_out layout: [0,N) Z as float; [N, N+N*D) q_with_st; then 2 losses.
  float* zout = out;
  float* qout = out + N;
  float* lout = out + N + (size_t)N * D;

  // workspace layout (floats): xsq[N], csq[K], partial[2048]
  float* xsq = (float*)d_ws;
  float* csq = xsq + N;
  float* partial = csq + K;

  rowsq_kernel<<<dim3(N / 8), dim3(256), 0, stream>>>(x, xsq, N);
  rowsq_kernel<<<dim3(K / 8), dim3(256), 0, stream>>>(cb, csq, K);
  argmin_kernel<<<dim3(N / BM), dim3(256), 0, stream>>>(x, cb, xsq, csq, zout);
  gather_kernel<<<dim3(2048), dim3(256), 0, stream>>>(x, cb, zout, qout, partial);
  loss_kernel<<<dim3(1), dim3(256), 0, stream>>>(partial, lout);
}

// Round 2
// 932.140 us; speedup vs baseline: 2.0985x; 2.0985x over previous
//
#include <hip/hip_runtime.h>

static constexpr int N = 32768;
static constexpr int K = 4096;
static constexpr int D = 512;

typedef _Float16 f16x8 __attribute__((ext_vector_type(8)));
typedef float f32x4 __attribute__((ext_vector_type(4)));

#define GLD16(GP, LP)                                                   \
  __builtin_amdgcn_global_load_lds(                                     \
      (const __attribute__((address_space(1))) void*)(GP),              \
      (__attribute__((address_space(3))) void*)(LP), 16, 0, 0)

// ---------------------------------------------------------------------------
// rowsq: replicate np pairwise sum of squares for 512-elem rows (round 1).
// ---------------------------------------------------------------------------
__global__ void rowsq_kernel(const float* __restrict__ a, float* __restrict__ out,
                             int rows) {
  int tid = threadIdx.x;
  int row = blockIdx.x * 8 + (tid >> 5);
  if (row >= rows) return;
  int l = tid & 31;
  const float* p = a + (size_t)row * D + (l >> 3) * 128 + (l & 7);
  float r = 0.f;
#pragma unroll
  for (int i = 0; i < 16; ++i) {
    float v = p[i * 8];
    r = __fadd_rn(r, __fmul_rn(v, v));
  }
  r = __fadd_rn(r, __shfl_xor(r, 1));
  r = __fadd_rn(r, __shfl_xor(r, 2));
  r = __fadd_rn(r, __shfl_xor(r, 4));
  r = __fadd_rn(r, __shfl_xor(r, 8));
  r = __fadd_rn(r, __shfl_xor(r, 16));
  if (l == 0) out[row] = r;
}

// ---------------------------------------------------------------------------
// convert: fp32 -> (hi, lo) f16 pair of scale*v. scale is an exact power of 2.
// ---------------------------------------------------------------------------
__global__ __launch_bounds__(256) void convert_kernel(
    const float* __restrict__ in, _Float16* __restrict__ hi,
    _Float16* __restrict__ lo, float scale, size_t n8) {
  for (size_t i = (size_t)blockIdx.x * 256 + threadIdx.x; i < n8;
       i += (size_t)gridDim.x * 256) {
    const float4* p = (const float4*)(in + i * 8);
    float4 a = p[0], b = p[1];
    float s[8] = {a.x, a.y, a.z, a.w, b.x, b.y, b.z, b.w};
    union { _Float16 h[8]; f16x8 v; } H, L;
#pragma unroll
    for (int j = 0; j < 8; ++j) {
      float t = s[j] * scale;
      H.h[j] = (_Float16)t;
      L.h[j] = (_Float16)(t - (float)H.h[j]);
    }
    *(f16x8*)(hi + i * 8) = H.v;
    *(f16x8*)(lo + i * 8) = L.v;
  }
}

// ---------------------------------------------------------------------------
// MFMA distance GEMM + per-block top-2 argmin.
// 128x128 tile, 256 threads (4 waves 2x2), BK=32, 16 K-steps.
// dot*4096 = S = xhi*chi + xhi*clo + xlo*chi  (f16 MFMA, fp32 acc)
// dist = (xsq - S/2048) + csq
// Writes per (row, 128-col panel): min1 val, min1 idx, min2 val.
// ---------------------------------------------------------------------------
__global__ __launch_bounds__(256) void mfma_argmin_kernel(
    const _Float16* __restrict__ xh, const _Float16* __restrict__ xl,
    const _Float16* __restrict__ ch, const _Float16* __restrict__ cl,
    const float* __restrict__ xsq, const float* __restrict__ csq,
    float* __restrict__ pv1, int* __restrict__ pi1, float* __restrict__ pv2) {
  __shared__ __align__(16) _Float16 Ah[128 * 32], Al[128 * 32];
  __shared__ __align__(16) _Float16 Bh[128 * 32], Bl[128 * 32];
  __shared__ float mbv1[128];
  __shared__ int mbi1[128];
  __shared__ float mbv2[128];

  // XCD-chunked mapping: each XCD owns 32 contiguous row panels, col-fastest.
  int bid = blockIdx.x;
  int xcd = bid & 7, j = bid >> 3;
  int rowPanel = xcd * 32 + (j >> 5);
  int colPanel = j & 31;

  int tid = threadIdx.x;
  int w = tid >> 6, l = tid & 63;
  int wr = w >> 1, wc = w & 1;
  int wrow = wr * 64, wcol = wc * 64;
  int rA = l & 15, g = l >> 4;

  const size_t rowBase = (size_t)rowPanel * 128;
  const size_t colBase = (size_t)colPanel * 128;

  f32x4 acc[4][4];
#pragma unroll
  for (int mi = 0; mi < 4; ++mi)
#pragma unroll
    for (int ni = 0; ni < 4; ++ni) acc[mi][ni] = (f32x4)0.f;

  const int r0 = tid >> 2, s0 = tid & 3;  // chunk c0 = tid; c1 = tid+256

  for (int kt = 0; kt < 16; ++kt) {
    __syncthreads();
    const int dOff = kt * 32;
    {
      const _Float16* a0 = xh + (rowBase + r0) * D + dOff + s0 * 8;
      GLD16(a0, &Ah[(size_t)tid * 8]);
      GLD16(a0 + (size_t)64 * D, &Ah[(size_t)(tid + 256) * 8]);
      const _Float16* a1 = xl + (rowBase + r0) * D + dOff + s0 * 8;
      GLD16(a1, &Al[(size_t)tid * 8]);
      GLD16(a1 + (size_t)64 * D, &Al[(size_t)(tid + 256) * 8]);
      const _Float16* b0 = ch + (colBase + r0) * D + dOff + s0 * 8;
      GLD16(b0, &Bh[(size_t)tid * 8]);
      GLD16(b0 + (size_t)64 * D, &Bh[(size_t)(tid + 256) * 8]);
      const _Float16* b1 = cl + (colBase + r0) * D + dOff + s0 * 8;
      GLD16(b1, &Bl[(size_t)tid * 8]);
      GLD16(b1 + (size_t)64 * D, &Bl[(size_t)(tid + 256) * 8]);
    }
    __syncthreads();

    f16x8 ah[4], al[4], bh[4], bl[4];
#pragma unroll
    for (int f = 0; f < 4; ++f) {
      int ra = (wrow + f * 16 + rA) * 32 + g * 8;
      int rb = (wcol + f * 16 + rA) * 32 + g * 8;
      ah[f] = *(const f16x8*)&Ah[ra];
      al[f] = *(const f16x8*)&Al[ra];
      bh[f] = *(const f16x8*)&Bh[rb];
      bl[f] = *(const f16x8*)&Bl[rb];
    }
#pragma unroll
    for (int mi = 0; mi < 4; ++mi)
#pragma unroll
      for (int ni = 0; ni < 4; ++ni) {
        acc[mi][ni] =
            __builtin_amdgcn_mfma_f32_16x16x32_f16(ah[mi], bh[ni], acc[mi][ni], 0, 0, 0);
        acc[mi][ni] =
            __builtin_amdgcn_mfma_f32_16x16x32_f16(ah[mi], bl[ni], acc[mi][ni], 0, 0, 0);
        acc[mi][ni] =
            __builtin_amdgcn_mfma_f32_16x16x32_f16(al[mi], bh[ni], acc[mi][ni], 0, 0, 0);
      }
  }

  // Epilogue: distances + per-row top-2 over this block's 128 cols.
  const float inv2048 = 1.0f / 2048.0f;
  float fv1[4][4], fv2[4][4];
  int fi1[4][4];
#pragma unroll
  for (int mi = 0; mi < 4; ++mi) {
#pragma unroll
    for (int r = 0; r < 4; ++r) {
      int row_l = wrow + mi * 16 + g * 4 + r;
      float xq = xsq[rowBase + row_l];
      float bv1 = 1e30f, bv2 = 1e30f;
      int bi1 = 0x7fffffff;
#pragma unroll
      for (int ni = 0; ni < 4; ++ni) {
        int col = (int)colBase + wcol + ni * 16 + rA;
        float S = acc[mi][ni][r];
        float dsc = (xq - S * inv2048) + csq[col];
        if (dsc < bv1 || (dsc == bv1 && col < bi1)) {
          bv2 = bv1; bv1 = dsc; bi1 = col;
        } else if (dsc < bv2) {
          bv2 = dsc;
        }
      }
      // merge across the 16 lanes sharing this row (rA = 0..15)
#pragma unroll
      for (int m = 1; m < 16; m <<= 1) {
        float ov1 = __shfl_xor(bv1, m);
        int oi1 = __shfl_xor(bi1, m);
        float ov2 = __shfl_xor(bv2, m);
        if (ov1 < bv1 || (ov1 == bv1 && oi1 < bi1)) {
          bv2 = fminf(bv1, ov2); bv1 = ov1; bi1 = oi1;
        } else {
          bv2 = fminf(bv2, ov1);
        }
      }
      fv1[mi][r] = bv1; fv2[mi][r] = bv2; fi1[mi][r] = bi1;
      if (wc == 1 && rA == 0) {
        mbv1[row_l] = bv1; mbi1[row_l] = bi1; mbv2[row_l] = bv2;
      }
    }
  }
  __syncthreads();
  if (wc == 0 && rA == 0) {
#pragma unroll
    for (int mi = 0; mi < 4; ++mi) {
#pragma unroll
      for (int r = 0; r < 4; ++r) {
        int row_l = wrow + mi * 16 + g * 4 + r;
        float bv1 = fv1[mi][r], bv2 = fv2[mi][r];
        int bi1 = fi1[mi][r];
        float ov1 = mbv1[row_l];
        int oi1 = mbi1[row_l];
        float ov2 = mbv2[row_l];
        if (ov1 < bv1 || (ov1 == bv1 && oi1 < bi1)) {
          bv2 = fminf(bv1, ov2); bv1 = ov1; bi1 = oi1;
        } else {
          bv2 = fminf(bv2, ov1);
        }
        size_t o = (rowBase + row_l) * 32 + colPanel;
        pv1[o] = bv1; pi1[o] = bi1; pv2[o] = bv2;
      }
    }
  }
}

// ---------------------------------------------------------------------------
// reduce: merge 32 col-panel partials per row -> Z; flag ambiguous rows.
// ---------------------------------------------------------------------------
__global__ __launch_bounds__(256) void reduce_kernel(
    const float* __restrict__ pv1, const int* __restrict__ pi1,
    const float* __restrict__ pv2, float* __restrict__ zout,
    int* __restrict__ ctr, int* __restrict__ list, float eps) {
  int row = blockIdx.x * 256 + threadIdx.x;
  if (row >= N) return;
  const float* p1 = pv1 + (size_t)row * 32;
  const int* pi = pi1 + (size_t)row * 32;
  const float* p2 = pv2 + (size_t)row * 32;
  float v1 = 1e30f, v2 = 1e30f;
  int i1 = 0x7fffffff;
  for (int jj = 0; jj < 32; ++jj) {
    float ov1 = p1[jj], ov2 = p2[jj];
    int oi1 = pi[jj];
    if (ov1 < v1 || (ov1 == v1 && oi1 < i1)) {
      v2 = fminf(v1, ov2); v1 = ov1; i1 = oi1;
    } else {
      v2 = fminf(v2, ov1);
    }
  }
  zout[row] = (float)i1;
  if (v2 - v1 < eps) {
    int p = atomicAdd(ctr, 1);
    if (p < 8192) list[p] = row;
  }
}

// ---------------------------------------------------------------------------
// rescore: exact fp32 argmin (bit-identical to round-1 arithmetic) for the
// few ambiguous rows. One block per listed row (grid-stride).
// ---------------------------------------------------------------------------
__global__ __launch_bounds__(256) void rescore_kernel(
    const float* __restrict__ x, const float* __restrict__ cb,
    const float* __restrict__ xsq, const float* __restrict__ csq,
    const int* __restrict__ ctr, const int* __restrict__ list,
    float* __restrict__ zout) {
  __shared__ float xrow[512];
  __shared__ float rv[256];
  __shared__ int ri[256];
  int cnt = *ctr;
  if (cnt > 8192) cnt = 8192;
  for (int it = blockIdx.x; it < cnt; it += gridDim.x) {
    int row = list[it];
    __syncthreads();
    for (int d = threadIdx.x; d < 512; d += 256) xrow[d] = x[(size_t)row * D + d];
    __syncthreads();
    float xq = xsq[row];
    float bv = 1e30f;
    int bi = 0x7fffffff;
    for (int k = threadIdx.x; k < K; k += 256) {
      const float* c = cb + (size_t)k * D;
      float acc = 0.f;
      for (int d = 0; d < 512; ++d) acc = fmaf(xrow[d], c[d], acc);
      float two = __fadd_rn(acc, acc);
      float t = __fsub_rn(xq, two);
      float dsc = __fadd_rn(t, csq[k]);
      if (dsc < bv) { bv = dsc; bi = k; }
    }
    rv[threadIdx.x] = bv;
    ri[threadIdx.x] = bi;
    __syncthreads();
    for (int s = 128; s > 0; s >>= 1) {
      if (threadIdx.x < s) {
        float ov = rv[threadIdx.x + s];
        int oi = ri[threadIdx.x + s];
        if (ov < rv[threadIdx.x] ||
            (ov == rv[threadIdx.x] && oi < ri[threadIdx.x])) {
          rv[threadIdx.x] = ov;
          ri[threadIdx.x] = oi;
        }
      }
      __syncthreads();
    }
    if (threadIdx.x == 0) zout[row] = (float)ri[0];
  }
}

// ---------------------------------------------------------------------------
// Fallback fp32 argmin (round-1 kernel, used only if ws is too small).
// ---------------------------------------------------------------------------
static constexpr int BM = 64;
static constexpr int BKc = 128;
static constexpr int BD = 32;

__global__ __launch_bounds__(256) void argmin_fp32_kernel(
    const float* __restrict__ x, const float* __restrict__ cb,
    const float* __restrict__ xsq, const float* __restrict__ csq,
    float* __restrict__ zout) {
  __shared__ float xs[BD][BM];
  __shared__ float cs[BD][BKc];
  __shared__ float mv[BM][16];
  __shared__ int mi[BM][16];

  int tid = threadIdx.x;
  int tx = tid & 15;
  int ty = tid >> 4;
  int row0 = blockIdx.x * BM;

  float bestv[4];
  int besti[4];
  float xsqr[4];
#pragma unroll
  for (int i = 0; i < 4; ++i) {
    bestv[i] = 3.4e38f;
    besti[i] = 0x7fffffff;
    xsqr[i] = xsq[row0 + ty * 4 + i];
  }

  for (int kt = 0; kt < K; kt += BKc) {
    float acc[4][8];
#pragma unroll
    for (int i = 0; i < 4; ++i)
#pragma unroll
      for (int jj = 0; jj < 8; ++jj) acc[i][jj] = 0.f;

    for (int dt = 0; dt < D; dt += BD) {
      __syncthreads();
      {
        int r = tid >> 2, d0 = (tid & 3) * 8;
        const float* src = x + (size_t)(row0 + r) * D + dt + d0;
        float4 v0 = *(const float4*)(src);
        float4 v1 = *(const float4*)(src + 4);
        xs[d0 + 0][r] = v0.x; xs[d0 + 1][r] = v0.y;
        xs[d0 + 2][r] = v0.z; xs[d0 + 3][r] = v0.w;
        xs[d0 + 4][r] = v1.x; xs[d0 + 5][r] = v1.y;
        xs[d0 + 6][r] = v1.z; xs[d0 + 7][r] = v1.w;
      }
      {
        int kk = tid >> 1, d0 = (tid & 1) * 16;
        const float* src = cb + (size_t)(kt + kk) * D + dt + d0;
        float4 v0 = *(const float4*)(src);
        float4 v1 = *(const float4*)(src + 4);
        float4 v2 = *(const float4*)(src + 8);
        float4 v3 = *(const float4*)(src + 12);
        cs[d0 + 0][kk] = v0.x;  cs[d0 + 1][kk] = v0.y;
        cs[d0 + 2][kk] = v0.z;  cs[d0 + 3][kk] = v0.w;
        cs[d0 + 4][kk] = v1.x;  cs[d0 + 5][kk] = v1.y;
        cs[d0 + 6][kk] = v1.z;  cs[d0 + 7][kk] = v1.w;
        cs[d0 + 8][kk] = v2.x;  cs[d0 + 9][kk] = v2.y;
        cs[d0 + 10][kk] = v2.z; cs[d0 + 11][kk] = v2.w;
        cs[d0 + 12][kk] = v3.x; cs[d0 + 13][kk] = v3.y;
        cs[d0 + 14][kk] = v3.z; cs[d0 + 15][kk] = v3.w;
      }
      __syncthreads();
#pragma unroll 4
      for (int d = 0; d < BD; ++d) {
        float xa[4], cv[8];
        *(float4*)&xa[0] = *(const float4*)&xs[d][ty * 4];
        *(float4*)&cv[0] = *(const float4*)&cs[d][tx * 8];
        *(float4*)&cv[4] = *(const float4*)&cs[d][tx * 8 + 4];
#pragma unroll
        for (int i = 0; i < 4; ++i)
#pragma unroll
          for (int jj = 0; jj < 8; ++jj)
            acc[i][jj] = fmaf(xa[i], cv[jj], acc[i][jj]);
      }
    }

#pragma unroll
    for (int jj = 0; jj < 8; ++jj) {
      int k = kt + tx * 8 + jj;
      float cq = csq[k];
#pragma unroll
      for (int i = 0; i < 4; ++i) {
        float two = __fadd_rn(acc[i][jj], acc[i][jj]);
        float t = __fsub_rn(xsqr[i], two);
        float dsc = __fadd_rn(t, cq);
        if (dsc < bestv[i]) { bestv[i] = dsc; besti[i] = k; }
      }
    }
  }

  __syncthreads();
#pragma unroll
  for (int i = 0; i < 4; ++i) {
    mv[ty * 4 + i][tx] = bestv[i];
    mi[ty * 4 + i][tx] = besti[i];
  }
  __syncthreads();
  if (tid < BM) {
    float bv = mv[tid][0];
    int bi = mi[tid][0];
#pragma unroll
    for (int t = 1; t < 16; ++t) {
      float v = mv[tid][t];
      int ii = mi[tid][t];
      if (v < bv || (v == bv && ii < bi)) { bv = v; bi = ii; }
    }
    zout[row0 + tid] = (float)bi;
  }
}

// ---------------------------------------------------------------------------
// gather + loss (round 1, unchanged).
// ---------------------------------------------------------------------------
__global__ __launch_bounds__(256) void gather_kernel(
    const float* __restrict__ x, const float* __restrict__ cb,
    const float* __restrict__ zf, float* __restrict__ qout,
    float* __restrict__ partial) {
  __shared__ float red[256];
  const size_t TOT4 = (size_t)N * D / 4;
  size_t t0 = (size_t)blockIdx.x * 256 + threadIdx.x;
  float lsum = 0.f;
  for (size_t f = t0; f < TOT4; f += (size_t)2048 * 256) {
    int n = (int)(f >> 7);
    int d4 = (int)(f & 127);
    int z = (int)zf[n];
    float4 xv = ((const float4*)x)[f];
    float4 qv = *(const float4*)(cb + (size_t)z * D + d4 * 4);
    float dx0 = __fsub_rn(qv.x, xv.x);
    float dx1 = __fsub_rn(qv.y, xv.y);
    float dx2 = __fsub_rn(qv.z, xv.z);
    float dx3 = __fsub_rn(qv.w, xv.w);
    float4 o;
    o.x = __fadd_rn(xv.x, dx0);
    o.y = __fadd_rn(xv.y, dx1);
    o.z = __fadd_rn(xv.z, dx2);
    o.w = __fadd_rn(xv.w, dx3);
    ((float4*)qout)[f] = o;
    lsum += dx0 * dx0 + dx1 * dx1 + dx2 * dx2 + dx3 * dx3;
  }
  red[threadIdx.x] = lsum;
  __syncthreads();
  for (int s = 128; s > 0; s >>= 1) {
    if (threadIdx.x < s) red[threadIdx.x] += red[threadIdx.x + s];
    __syncthreads();
  }
  if (threadIdx.x == 0) partial[blockIdx.x] = red[0];
}

__global__ __launch_bounds__(256) void loss_kernel(const float* __restrict__ partial,
                                                   float* __restrict__ loss_out) {
  __shared__ float red[256];
  float s = 0.f;
  for (int i = threadIdx.x; i < 2048; i += 256) s += partial[i];
  red[threadIdx.x] = s;
  __syncthreads();
  for (int k = 128; k > 0; k >>= 1) {
    if (threadIdx.x < k) red[threadIdx.x] += red[threadIdx.x + k];
    __syncthreads();
  }
  if (threadIdx.x == 0) {
    float m = red[0] / (float)((size_t)N * D);
    loss_out[0] = m;
    loss_out[1] = m;
  }
}

// ---------------------------------------------------------------------------
// workspace layout (bytes)
// ---------------------------------------------------------------------------
static constexpr size_t OFF_XSQ = 0;                       // N*4
static constexpr size_t OFF_CSQ = 131072;                  // K*4
static constexpr size_t OFF_PART = 147456;                 // 2048*4
static constexpr size_t OFF_CTR = 155648;                  // 256
static constexpr size_t OFF_LIST = 155904;                 // 8192*4
static constexpr size_t OFF_PV1 = 188672;                  // N*32*4
static constexpr size_t OFF_PI1 = OFF_PV1 + 4194304;
static constexpr size_t OFF_PV2 = OFF_PI1 + 4194304;
static constexpr size_t OFF_CHI = OFF_PV2 + 4194304;       // K*D*2
static constexpr size_t OFF_CLO = OFF_CHI + 4194304;
static constexpr size_t WS_REQ = OFF_CLO + 4194304;        // ~20.2 MB

extern "C" void kernel_launch(void* const* d_in, const int* in_sizes, int n_in,
                              void* d_out, int out_size, void* d_ws, size_t ws_size,
                              hipStream_t stream) {
  const float* x = (const float*)d_in[0];
  const float* cb = (const float*)d_in[1];
  float* out = (float*)d_out;

  float* zout = out;
  float* qout = out + N;
  float* lout = out + N + (size_t)N * D;

  char* ws = (char*)d_ws;
  float* xsq = (float*)(ws + OFF_XSQ);
  float* csq = (float*)(ws + OFF_CSQ);
  float* partial = (float*)(ws + OFF_PART);

  rowsq_kernel<<<dim3(N / 8), dim3(256), 0, stream>>>(x, xsq, N);
  rowsq_kernel<<<dim3(K / 8), dim3(256), 0, stream>>>(cb, csq, K);

  if (ws_size >= WS_REQ) {
    int* ctr = (int*)(ws + OFF_CTR);
    int* list = (int*)(ws + OFF_LIST);
    float* pv1 = (float*)(ws + OFF_PV1);
    int* pi1 = (int*)(ws + OFF_PI1);
    float* pv2 = (float*)(ws + OFF_PV2);
    _Float16* chi = (_Float16*)(ws + OFF_CHI);
    _Float16* clo = (_Float16*)(ws + OFF_CLO);

    // x hi/lo f16 stashed in the q output region (exactly N*D*4 bytes),
    // fully overwritten by gather_kernel afterwards.
    _Float16* xhi = (_Float16*)qout;
    _Float16* xlo = xhi + (size_t)N * D;

    convert_kernel<<<dim3(4096), dim3(256), 0, stream>>>(x, xhi, xlo, 16.0f,
                                                         (size_t)N * D / 8);
    convert_kernel<<<dim3(1024), dim3(256), 0, stream>>>(cb, chi, clo, 256.0f,
                                                         (size_t)K * D / 8);
    hipMemsetAsync(ctr, 0, sizeof(int), stream);
    mfma_argmin_kernel<<<dim3((N / 128) * (K / 128)), dim3(256), 0, stream>>>(
        xhi, xlo, chi, clo, xsq, csq, pv1, pi1, pv2);
    reduce_kernel<<<dim3(N / 256), dim3(256), 0, stream>>>(pv1, pi1, pv2, zout,
                                                           ctr, list, 3e-4f);
    rescore_kernel<<<dim3(128), dim3(256), 0, stream>>>(x, cb, xsq, csq, ctr,
                                                        list, zout);
  } else {
    argmin_fp32_kernel<<<dim3(N / BM), dim3(256), 0, stream>>>(x, cb, xsq, csq,
                                                               zout);
  }

  gather_kernel<<<dim3(2048), dim3(256), 0, stream>>>(x, cb, zout, qout, partial);
  loss_kernel<<<dim3(1), dim3(256), 0, stream>>>(partial, lout);
}

// Round 3
// 931.615 us; speedup vs baseline: 2.0997x; 1.0006x over previous
//
#include <hip/hip_runtime.h>

static constexpr int N = 32768;
static constexpr int K = 4096;
static constexpr int D = 512;

typedef _Float16 f16x8 __attribute__((ext_vector_type(8)));
typedef float f32x4 __attribute__((ext_vector_type(4)));

#define GLD16(GP, LP)                                                   \
  __builtin_amdgcn_global_load_lds(                                     \
      (const __attribute__((address_space(1))) void*)(GP),              \
      (__attribute__((address_space(3))) void*)(LP), 16, 0, 0)

// ---------------------------------------------------------------------------
// rowsq: replicate np pairwise sum of squares for 512-elem rows.
// ---------------------------------------------------------------------------
__global__ void rowsq_kernel(const float* __restrict__ a, float* __restrict__ out,
                             int rows) {
  int tid = threadIdx.x;
  int row = blockIdx.x * 8 + (tid >> 5);
  if (row >= rows) return;
  int l = tid & 31;
  const float* p = a + (size_t)row * D + (l >> 3) * 128 + (l & 7);
  float r = 0.f;
#pragma unroll
  for (int i = 0; i < 16; ++i) {
    float v = p[i * 8];
    r = __fadd_rn(r, __fmul_rn(v, v));
  }
  r = __fadd_rn(r, __shfl_xor(r, 1));
  r = __fadd_rn(r, __shfl_xor(r, 2));
  r = __fadd_rn(r, __shfl_xor(r, 4));
  r = __fadd_rn(r, __shfl_xor(r, 8));
  r = __fadd_rn(r, __shfl_xor(r, 16));
  if (l == 0) out[row] = r;
}

// ---------------------------------------------------------------------------
// convert: fp32 -> (hi, lo) f16 pair of scale*v. scale is an exact power of 2.
// ---------------------------------------------------------------------------
__global__ __launch_bounds__(256) void convert_kernel(
    const float* __restrict__ in, _Float16* __restrict__ hi,
    _Float16* __restrict__ lo, float scale, size_t n8) {
  for (size_t i = (size_t)blockIdx.x * 256 + threadIdx.x; i < n8;
       i += (size_t)gridDim.x * 256) {
    const float4* p = (const float4*)(in + i * 8);
    float4 a = p[0], b = p[1];
    float s[8] = {a.x, a.y, a.z, a.w, b.x, b.y, b.z, b.w};
    union { _Float16 h[8]; f16x8 v; } H, L;
#pragma unroll
    for (int j = 0; j < 8; ++j) {
      float t = s[j] * scale;
      H.h[j] = (_Float16)t;
      L.h[j] = (_Float16)(t - (float)H.h[j]);
    }
    *(f16x8*)(hi + i * 8) = H.v;
    *(f16x8*)(lo + i * 8) = L.v;
  }
}

// ---------------------------------------------------------------------------
// MFMA distance GEMM + per-block top-2 argmin.
// 128x128 tile, 256 threads (4 waves 2x2), BK=32, 16 K-steps.
// dot*4096 = S = xhi*chi + xhi*clo + xlo*chi  (f16 MFMA, fp32 acc)
// dist = (xsq - S/2048) + csq
//
// LDS swizzle (T2, both-sides-or-neither): rows are 64B = 4 chunks of 16B.
//   physical_chunk = logical_chunk ^ ((row>>1)&3)
// Store side: GLD16 dest stays linear; global SOURCE chunk is pre-swizzled
// (cs = s0 ^ ((r0>>1)&3); same XOR for row and row+64). Read side applies the
// same XOR. Reader banks: 64 lanes -> 2 per bank-pair (conflict-free).
// ---------------------------------------------------------------------------
__global__ __launch_bounds__(256) void mfma_argmin_kernel(
    const _Float16* __restrict__ xh, const _Float16* __restrict__ xl,
    const _Float16* __restrict__ ch, const _Float16* __restrict__ cl,
    const float* __restrict__ xsq, const float* __restrict__ csq,
    float* __restrict__ pv1, int* __restrict__ pi1, float* __restrict__ pv2) {
  __shared__ __align__(16) _Float16 Ah[128 * 32], Al[128 * 32];
  __shared__ __align__(16) _Float16 Bh[128 * 32], Bl[128 * 32];
  __shared__ float mbv1[128];
  __shared__ int mbi1[128];
  __shared__ float mbv2[128];

  // XCD-chunked mapping: each XCD owns 32 contiguous row panels, col-fastest.
  int bid = blockIdx.x;
  int xcd = bid & 7, j = bid >> 3;
  int rowPanel = xcd * 32 + (j >> 5);
  int colPanel = j & 31;

  int tid = threadIdx.x;
  int w = tid >> 6, l = tid & 63;
  int wr = w >> 1, wc = w & 1;
  int wrow = wr * 64, wcol = wc * 64;
  int rA = l & 15, g = l >> 4;

  const size_t rowBase = (size_t)rowPanel * 128;
  const size_t colBase = (size_t)colPanel * 128;

  f32x4 acc[4][4];
#pragma unroll
  for (int mi = 0; mi < 4; ++mi)
#pragma unroll
    for (int ni = 0; ni < 4; ++ni) acc[mi][ni] = (f32x4)0.f;

  const int r0 = tid >> 2, s0 = tid & 3;
  const int cs = s0 ^ ((r0 >> 1) & 3);  // pre-swizzled source chunk
  // read-side swizzled chunk offset (f16 units): depends on rA only
  const int swz = (g ^ ((rA >> 1) & 3)) * 8;

  for (int kt = 0; kt < 16; ++kt) {
    __syncthreads();
    const int dOff = kt * 32;
    {
      const _Float16* a0 = xh + (rowBase + r0) * D + dOff + cs * 8;
      GLD16(a0, &Ah[(size_t)tid * 8]);
      GLD16(a0 + (size_t)64 * D, &Ah[(size_t)(tid + 256) * 8]);
      const _Float16* a1 = xl + (rowBase + r0) * D + dOff + cs * 8;
      GLD16(a1, &Al[(size_t)tid * 8]);
      GLD16(a1 + (size_t)64 * D, &Al[(size_t)(tid + 256) * 8]);
      const _Float16* b0 = ch + (colBase + r0) * D + dOff + cs * 8;
      GLD16(b0, &Bh[(size_t)tid * 8]);
      GLD16(b0 + (size_t)64 * D, &Bh[(size_t)(tid + 256) * 8]);
      const _Float16* b1 = cl + (colBase + r0) * D + dOff + cs * 8;
      GLD16(b1, &Bl[(size_t)tid * 8]);
      GLD16(b1 + (size_t)64 * D, &Bl[(size_t)(tid + 256) * 8]);
    }
    __syncthreads();

    f16x8 ah[4], al[4], bh[4], bl[4];
#pragma unroll
    for (int f = 0; f < 4; ++f) {
      int ra = (wrow + f * 16 + rA) * 32 + swz;
      int rb = (wcol + f * 16 + rA) * 32 + swz;
      ah[f] = *(const f16x8*)&Ah[ra];
      al[f] = *(const f16x8*)&Al[ra];
      bh[f] = *(const f16x8*)&Bh[rb];
      bl[f] = *(const f16x8*)&Bl[rb];
    }
#pragma unroll
    for (int mi = 0; mi < 4; ++mi)
#pragma unroll
      for (int ni = 0; ni < 4; ++ni) {
        acc[mi][ni] =
            __builtin_amdgcn_mfma_f32_16x16x32_f16(ah[mi], bh[ni], acc[mi][ni], 0, 0, 0);
        acc[mi][ni] =
            __builtin_amdgcn_mfma_f32_16x16x32_f16(ah[mi], bl[ni], acc[mi][ni], 0, 0, 0);
        acc[mi][ni] =
            __builtin_amdgcn_mfma_f32_16x16x32_f16(al[mi], bh[ni], acc[mi][ni], 0, 0, 0);
      }
  }

  // Epilogue: distances + per-row top-2 over this block's 128 cols.
  const float inv2048 = 1.0f / 2048.0f;
  float fv1[4][4], fv2[4][4];
  int fi1[4][4];
#pragma unroll
  for (int mi = 0; mi < 4; ++mi) {
#pragma unroll
    for (int r = 0; r < 4; ++r) {
      int row_l = wrow + mi * 16 + g * 4 + r;
      float xq = xsq[rowBase + row_l];
      float bv1 = 1e30f, bv2 = 1e30f;
      int bi1 = 0x7fffffff;
#pragma unroll
      for (int ni = 0; ni < 4; ++ni) {
        int col = (int)colBase + wcol + ni * 16 + rA;
        float S = acc[mi][ni][r];
        float dsc = (xq - S * inv2048) + csq[col];
        if (dsc < bv1 || (dsc == bv1 && col < bi1)) {
          bv2 = bv1; bv1 = dsc; bi1 = col;
        } else if (dsc < bv2) {
          bv2 = dsc;
        }
      }
      // merge across the 16 lanes sharing this row (rA = 0..15)
#pragma unroll
      for (int m = 1; m < 16; m <<= 1) {
        float ov1 = __shfl_xor(bv1, m);
        int oi1 = __shfl_xor(bi1, m);
        float ov2 = __shfl_xor(bv2, m);
        if (ov1 < bv1 || (ov1 == bv1 && oi1 < bi1)) {
          bv2 = fminf(bv1, ov2); bv1 = ov1; bi1 = oi1;
        } else {
          bv2 = fminf(bv2, ov1);
        }
      }
      fv1[mi][r] = bv1; fv2[mi][r] = bv2; fi1[mi][r] = bi1;
      if (wc == 1 && rA == 0) {
        mbv1[row_l] = bv1; mbi1[row_l] = bi1; mbv2[row_l] = bv2;
      }
    }
  }
  __syncthreads();
  if (wc == 0 && rA == 0) {
#pragma unroll
    for (int mi = 0; mi < 4; ++mi) {
#pragma unroll
      for (int r = 0; r < 4; ++r) {
        int row_l = wrow + mi * 16 + g * 4 + r;
        float bv1 = fv1[mi][r], bv2 = fv2[mi][r];
        int bi1 = fi1[mi][r];
        float ov1 = mbv1[row_l];
        int oi1 = mbi1[row_l];
        float ov2 = mbv2[row_l];
        if (ov1 < bv1 || (ov1 == bv1 && oi1 < bi1)) {
          bv2 = fminf(bv1, ov2); bv1 = ov1; bi1 = oi1;
        } else {
          bv2 = fminf(bv2, ov1);
        }
        // panel-major layout: coalesced reads in reduce_kernel
        size_t o = (size_t)colPanel * N + (rowBase + row_l);
        pv1[o] = bv1; pi1[o] = bi1; pv2[o] = bv2;
      }
    }
  }
}

// ---------------------------------------------------------------------------
// reduce: merge 32 col-panel partials per row -> Z; flag ambiguous rows.
// Panel-major partials: thread `row` reads pv[jj*N + row] (coalesced).
// ---------------------------------------------------------------------------
__global__ __launch_bounds__(256) void reduce_kernel(
    const float* __restrict__ pv1, const int* __restrict__ pi1,
    const float* __restrict__ pv2, float* __restrict__ zout,
    int* __restrict__ ctr, int* __restrict__ list, float eps) {
  int row = blockIdx.x * 256 + threadIdx.x;
  if (row >= N) return;
  float v1 = 1e30f, v2 = 1e30f;
  int i1 = 0x7fffffff;
  for (int jj = 0; jj < 32; ++jj) {
    float ov1 = pv1[(size_t)jj * N + row];
    float ov2 = pv2[(size_t)jj * N + row];
    int oi1 = pi1[(size_t)jj * N + row];
    if (ov1 < v1 || (ov1 == v1 && oi1 < i1)) {
      v2 = fminf(v1, ov2); v1 = ov1; i1 = oi1;
    } else {
      v2 = fminf(v2, ov1);
    }
  }
  zout[row] = (float)i1;
  if (v2 - v1 < eps) {
    int p = atomicAdd(ctr, 1);
    if (p < 8192) list[p] = row;
  }
}

// ---------------------------------------------------------------------------
// rescore: exact fp32 argmin (bit-identical to round-1 arithmetic) for the
// few ambiguous rows. One block per listed row (grid-stride).
// ---------------------------------------------------------------------------
__global__ __launch_bounds__(256) void rescore_kernel(
    const float* __restrict__ x, const float* __restrict__ cb,
    const float* __restrict__ xsq, const float* __restrict__ csq,
    const int* __restrict__ ctr, const int* __restrict__ list,
    float* __restrict__ zout) {
  __shared__ float xrow[512];
  __shared__ float rv[256];
  __shared__ int ri[256];
  int cnt = *ctr;
  if (cnt > 8192) cnt = 8192;
  for (int it = blockIdx.x; it < cnt; it += gridDim.x) {
    int row = list[it];
    __syncthreads();
    for (int d = threadIdx.x; d < 512; d += 256) xrow[d] = x[(size_t)row * D + d];
    __syncthreads();
    float xq = xsq[row];
    float bv = 1e30f;
    int bi = 0x7fffffff;
    for (int k = threadIdx.x; k < K; k += 256) {
      const float* c = cb + (size_t)k * D;
      float acc = 0.f;
      for (int d = 0; d < 512; ++d) acc = fmaf(xrow[d], c[d], acc);
      float two = __fadd_rn(acc, acc);
      float t = __fsub_rn(xq, two);
      float dsc = __fadd_rn(t, csq[k]);
      if (dsc < bv) { bv = dsc; bi = k; }
    }
    rv[threadIdx.x] = bv;
    ri[threadIdx.x] = bi;
    __syncthreads();
    for (int s = 128; s > 0; s >>= 1) {
      if (threadIdx.x < s) {
        float ov = rv[threadIdx.x + s];
        int oi = ri[threadIdx.x + s];
        if (ov < rv[threadIdx.x] ||
            (ov == rv[threadIdx.x] && oi < ri[threadIdx.x])) {
          rv[threadIdx.x] = ov;
          ri[threadIdx.x] = oi;
        }
      }
      __syncthreads();
    }
    if (threadIdx.x == 0) zout[row] = (float)ri[0];
  }
}

// ---------------------------------------------------------------------------
// Fallback fp32 argmin (round-1 kernel, used only if ws is too small).
// ---------------------------------------------------------------------------
static constexpr int BM = 64;
static constexpr int BKc = 128;
static constexpr int BD = 32;

__global__ __launch_bounds__(256) void argmin_fp32_kernel(
    const float* __restrict__ x, const float* __restrict__ cb,
    const float* __restrict__ xsq, const float* __restrict__ csq,
    float* __restrict__ zout) {
  __shared__ float xs[BD][BM];
  __shared__ float cs_[BD][BKc];
  __shared__ float mv[BM][16];
  __shared__ int mi[BM][16];

  int tid = threadIdx.x;
  int tx = tid & 15;
  int ty = tid >> 4;
  int row0 = blockIdx.x * BM;

  float bestv[4];
  int besti[4];
  float xsqr[4];
#pragma unroll
  for (int i = 0; i < 4; ++i) {
    bestv[i] = 3.4e38f;
    besti[i] = 0x7fffffff;
    xsqr[i] = xsq[row0 + ty * 4 + i];
  }

  for (int kt = 0; kt < K; kt += BKc) {
    float acc[4][8];
#pragma unroll
    for (int i = 0; i < 4; ++i)
#pragma unroll
      for (int jj = 0; jj < 8; ++jj) acc[i][jj] = 0.f;

    for (int dt = 0; dt < D; dt += BD) {
      __syncthreads();
      {
        int r = tid >> 2, d0 = (tid & 3) * 8;
        const float* src = x + (size_t)(row0 + r) * D + dt + d0;
        float4 v0 = *(const float4*)(src);
        float4 v1 = *(const float4*)(src + 4);
        xs[d0 + 0][r] = v0.x; xs[d0 + 1][r] = v0.y;
        xs[d0 + 2][r] = v0.z; xs[d0 + 3][r] = v0.w;
        xs[d0 + 4][r] = v1.x; xs[d0 + 5][r] = v1.y;
        xs[d0 + 6][r] = v1.z; xs[d0 + 7][r] = v1.w;
      }
      {
        int kk = tid >> 1, d0 = (tid & 1) * 16;
        const float* src = cb + (size_t)(kt + kk) * D + dt + d0;
        float4 v0 = *(const float4*)(src);
        float4 v1 = *(const float4*)(src + 4);
        float4 v2 = *(const float4*)(src + 8);
        float4 v3 = *(const float4*)(src + 12);
        cs_[d0 + 0][kk] = v0.x;  cs_[d0 + 1][kk] = v0.y;
        cs_[d0 + 2][kk] = v0.z;  cs_[d0 + 3][kk] = v0.w;
        cs_[d0 + 4][kk] = v1.x;  cs_[d0 + 5][kk] = v1.y;
        cs_[d0 + 6][kk] = v1.z;  cs_[d0 + 7][kk] = v1.w;
        cs_[d0 + 8][kk] = v2.x;  cs_[d0 + 9][kk] = v2.y;
        cs_[d0 + 10][kk] = v2.z; cs_[d0 + 11][kk] = v2.w;
        cs_[d0 + 12][kk] = v3.x; cs_[d0 + 13][kk] = v3.y;
        cs_[d0 + 14][kk] = v3.z; cs_[d0 + 15][kk] = v3.w;
      }
      __syncthreads();
#pragma unroll 4
      for (int d = 0; d < BD; ++d) {
        float xa[4], cv[8];
        *(float4*)&xa[0] = *(const float4*)&xs[d][ty * 4];
        *(float4*)&cv[0] = *(const float4*)&cs_[d][tx * 8];
        *(float4*)&cv[4] = *(const float4*)&cs_[d][tx * 8 + 4];
#pragma unroll
        for (int i = 0; i < 4; ++i)
#pragma unroll
          for (int jj = 0; jj < 8; ++jj)
            acc[i][jj] = fmaf(xa[i], cv[jj], acc[i][jj]);
      }
    }

#pragma unroll
    for (int jj = 0; jj < 8; ++jj) {
      int k = kt + tx * 8 + jj;
      float cq = csq[k];
#pragma unroll
      for (int i = 0; i < 4; ++i) {
        float two = __fadd_rn(acc[i][jj], acc[i][jj]);
        float t = __fsub_rn(xsqr[i], two);
        float dsc = __fadd_rn(t, cq);
        if (dsc < bestv[i]) { bestv[i] = dsc; besti[i] = k; }
      }
    }
  }

  __syncthreads();
#pragma unroll
  for (int i = 0; i < 4; ++i) {
    mv[ty * 4 + i][tx] = bestv[i];
    mi[ty * 4 + i][tx] = besti[i];
  }
  __syncthreads();
  if (tid < BM) {
    float bv = mv[tid][0];
    int bi = mi[tid][0];
#pragma unroll
    for (int t = 1; t < 16; ++t) {
      float v = mv[tid][t];
      int ii = mi[tid][t];
      if (v < bv || (v == bv && ii < bi)) { bv = v; bi = ii; }
    }
    zout[row0 + tid] = (float)bi;
  }
}

// ---------------------------------------------------------------------------
// gather + loss.
// ---------------------------------------------------------------------------
__global__ __launch_bounds__(256) void gather_kernel(
    const float* __restrict__ x, const float* __restrict__ cb,
    const float* __restrict__ zf, float* __restrict__ qout,
    float* __restrict__ partial) {
  __shared__ float red[256];
  const size_t TOT4 = (size_t)N * D / 4;
  size_t t0 = (size_t)blockIdx.x * 256 + threadIdx.x;
  float lsum = 0.f;
  for (size_t f = t0; f < TOT4; f += (size_t)2048 * 256) {
    int n = (int)(f >> 7);
    int d4 = (int)(f & 127);
    int z = (int)zf[n];
    float4 xv = ((const float4*)x)[f];
    float4 qv = *(const float4*)(cb + (size_t)z * D + d4 * 4);
    float dx0 = __fsub_rn(qv.x, xv.x);
    float dx1 = __fsub_rn(qv.y, xv.y);
    float dx2 = __fsub_rn(qv.z, xv.z);
    float dx3 = __fsub_rn(qv.w, xv.w);
    float4 o;
    o.x = __fadd_rn(xv.x, dx0);
    o.y = __fadd_rn(xv.y, dx1);
    o.z = __fadd_rn(xv.z, dx2);
    o.w = __fadd_rn(xv.w, dx3);
    ((float4*)qout)[f] = o;
    lsum += dx0 * dx0 + dx1 * dx1 + dx2 * dx2 + dx3 * dx3;
  }
  red[threadIdx.x] = lsum;
  __syncthreads();
  for (int s = 128; s > 0; s >>= 1) {
    if (threadIdx.x < s) red[threadIdx.x] += red[threadIdx.x + s];
    __syncthreads();
  }
  if (threadIdx.x == 0) partial[blockIdx.x] = red[0];
}

__global__ __launch_bounds__(256) void loss_kernel(const float* __restrict__ partial,
                                                   float* __restrict__ loss_out) {
  __shared__ float red[256];
  float s = 0.f;
  for (int i = threadIdx.x; i < 2048; i += 256) s += partial[i];
  red[threadIdx.x] = s;
  __syncthreads();
  for (int k = 128; k > 0; k >>= 1) {
    if (threadIdx.x < k) red[threadIdx.x] += red[threadIdx.x + k];
    __syncthreads();
  }
  if (threadIdx.x == 0) {
    float m = red[0] / (float)((size_t)N * D);
    loss_out[0] = m;
    loss_out[1] = m;
  }
}

// ---------------------------------------------------------------------------
// workspace layout (bytes)
// ---------------------------------------------------------------------------
static constexpr size_t OFF_XSQ = 0;                       // N*4
static constexpr size_t OFF_CSQ = 131072;                  // K*4
static constexpr size_t OFF_PART = 147456;                 // 2048*4
static constexpr size_t OFF_CTR = 155648;                  // 256
static constexpr size_t OFF_LIST = 155904;                 // 8192*4
static constexpr size_t OFF_PV1 = 188672;                  // N*32*4
static constexpr size_t OFF_PI1 = OFF_PV1 + 4194304;
static constexpr size_t OFF_PV2 = OFF_PI1 + 4194304;
static constexpr size_t OFF_CHI = OFF_PV2 + 4194304;       // K*D*2
static constexpr size_t OFF_CLO = OFF_CHI + 4194304;
static constexpr size_t WS_REQ = OFF_CLO + 4194304;        // ~20.2 MB

extern "C" void kernel_launch(void* const* d_in, const int* in_sizes, int n_in,
                              void* d_out, int out_size, void* d_ws, size_t ws_size,
                              hipStream_t stream) {
  const float* x = (const float*)d_in[0];
  const float* cb = (const float*)d_in[1];
  float* out = (float*)d_out;

  float* zout = out;
  float* qout = out + N;
  float* lout = out + N + (size_t)N * D;

  char* ws = (char*)d_ws;
  float* xsq = (float*)(ws + OFF_XSQ);
  float* csq = (float*)(ws + OFF_CSQ);
  float* partial = (float*)(ws + OFF_PART);

  rowsq_kernel<<<dim3(N / 8), dim3(256), 0, stream>>>(x, xsq, N);
  rowsq_kernel<<<dim3(K / 8), dim3(256), 0, stream>>>(cb, csq, K);

  if (ws_size >= WS_REQ) {
    int* ctr = (int*)(ws + OFF_CTR);
    int* list = (int*)(ws + OFF_LIST);
    float* pv1 = (float*)(ws + OFF_PV1);
    int* pi1 = (int*)(ws + OFF_PI1);
    float* pv2 = (float*)(ws + OFF_PV2);
    _Float16* chi = (_Float16*)(ws + OFF_CHI);
    _Float16* clo = (_Float16*)(ws + OFF_CLO);

    _Float16* xhi = (_Float16*)qout;
    _Float16* xlo = xhi + (size_t)N * D;

    convert_kernel<<<dim3(4096), dim3(256), 0, stream>>>(x, xhi, xlo, 16.0f,
                                                         (size_t)N * D / 8);
    convert_kernel<<<dim3(1024), dim3(256), 0, stream>>>(cb, chi, clo, 256.0f,
                                                         (size_t)K * D / 8);
    hipMemsetAsync(ctr, 0, sizeof(int), stream);
    mfma_argmin_kernel<<<dim3((N / 128) * (K / 128)), dim3(256), 0, stream>>>(
        xhi, xlo, chi, clo, xsq, csq, pv1, pi1, pv2);
    reduce_kernel<<<dim3(N / 256), dim3(256), 0, stream>>>(pv1, pi1, pv2, zout,
                                                           ctr, list, 3e-4f);
    rescore_kernel<<<dim3(128), dim3(256), 0, stream>>>(x, cb, xsq, csq, ctr,
                                                        list, zout);
  } else {
    argmin_fp32_kernel<<<dim3(N / BM), dim3(256), 0, stream>>>(x, cb, xsq, csq,
                                                               zout);
  }

  gather_kernel<<<dim3(2048), dim3(256), 0, stream>>>(x, cb, zout, qout, partial);
  loss_kernel<<<dim3(1), dim3(256), 0, stream>>>(partial, lout);
}